// Round 15
// baseline (780.992 us; speedup 1.0000x reference)
//
#include <hip/hip_runtime.h>

typedef __bf16 bf16;
typedef __bf16 bf16x8 __attribute__((ext_vector_type(8)));
typedef float f32x4 __attribute__((ext_vector_type(4)));

#define S_NB 50

// ---------------- weight pre-shuffle: f32 -> bf16 MFMA B-fragment layout ----
__global__ __launch_bounds__(256) void shuffle_w(const float* __restrict__ gatW,
                                                 bf16* __restrict__ ws) {
  int tid = blockIdx.x * 256 + threadIdx.x;
  if (tid >= 6 * 512) return;
  int mat = tid >> 9;
  int rem = tid & 511;
  int ks = rem >> 8;
  int nt = (rem >> 6) & 3;
  int lane = rem & 63;
  int t = mat >> 1, p = (mat & 1) + 1;
  const float* src = gatW + (size_t)(t * 4 + p) * 4096;
  int n = nt * 16 + (lane & 15);
  int kb = ks * 32 + (lane >> 4) * 8;
  bf16x8 v;
#pragma unroll
  for (int e = 0; e < 8; ++e) v[e] = (bf16)src[(kb + e) * 64 + n];
  *reinterpret_cast<bf16x8*>(ws + mat * 4096 + ((ks * 4 + nt) * 64 + lane) * 8) = v;
}

// inst mapping: 0:U(u_movies,item | node user[uids])  1:M(m_querys,query | item[mids])
//               2:M(m_users,user | item[mids])        3:Q(q_movies,item | query[qids])

// ---- K2: scores. one wave per (inst, b, m-tile). no LDS, no barriers. ------
__global__ __launch_bounds__(256) void k_scores(
    const int* __restrict__ uids, const int* __restrict__ qids,
    const int* __restrict__ mids, const int* __restrict__ u_movies,
    const int* __restrict__ m_querys, const int* __restrict__ m_users,
    const int* __restrict__ q_movies, const float* __restrict__ user_t,
    const float* __restrict__ item_t, const float* __restrict__ query_t,
    const float* __restrict__ gatW, const float* __restrict__ gatB,
    const bf16* __restrict__ wfrag, float* __restrict__ scores, int B) {
  int w = (blockIdx.x * 256 + threadIdx.x) >> 6;
  int lane = threadIdx.x & 63;
  int m = w & 3;
  int ib = w >> 2;            // inst*B + b
  int inst = ib / B;
  int b = ib - inst * B;

  const int* idx; const float* nbt; const float* ndt; int ndid; int woff;
  if (inst == 0) { idx = u_movies; nbt = item_t; ndt = user_t; ndid = uids[b]; woff = 0; }
  else if (inst == 1) { idx = m_querys; nbt = query_t; ndt = item_t; ndid = mids[b]; woff = 1; }
  else if (inst == 2) { idx = m_users; nbt = user_t; ndt = item_t; ndid = mids[b]; woff = 1; }
  else { idx = q_movies; nbt = item_t; ndt = query_t; ndid = qids[b]; woff = 2; }
  const float* Wt = gatW + (size_t)woff * 4 * 4096;
  const float* bt = gatB + woff * 256;
  const bf16* fr = wfrag + woff * 8192;

  // qp[col=lane] = relu(node @ W0 + b0), node broadcast via shuffle
  float nd = ndt[(size_t)ndid * 64 + lane];
  float q0 = 0.f, q1 = 0.f, q2 = 0.f, q3 = 0.f;
#pragma unroll 4
  for (int k = 0; k < 64; k += 4) {
    q0 += __shfl(nd, k, 64) * Wt[k * 64 + lane];
    q1 += __shfl(nd, k + 1, 64) * Wt[(k + 1) * 64 + lane];
    q2 += __shfl(nd, k + 2, 64) * Wt[(k + 2) * 64 + lane];
    q3 += __shfl(nd, k + 3, 64) * Wt[(k + 3) * 64 + lane];
  }
  float qv_own = fmaxf((((q0 + q1) + q2) + q3) + bt[lane], 0.f);

  // A fragments for this m-tile (rows 50..63 -> id 0 = zero row)
  int c15 = lane & 15, g = lane >> 4;
  int arow = m * 16 + c15;
  int id = (arow < S_NB) ? idx[b * S_NB + arow] : 0;
  const float* rowp = nbt + (size_t)id * 64;
  float4 f0 = *reinterpret_cast<const float4*>(rowp + g * 8);
  float4 f1 = *reinterpret_cast<const float4*>(rowp + g * 8 + 4);
  float4 f2 = *reinterpret_cast<const float4*>(rowp + 32 + g * 8);
  float4 f3 = *reinterpret_cast<const float4*>(rowp + 32 + g * 8 + 4);
  bf16x8 a0f, a1f;
  a0f[0] = (bf16)f0.x; a0f[1] = (bf16)f0.y; a0f[2] = (bf16)f0.z; a0f[3] = (bf16)f0.w;
  a0f[4] = (bf16)f1.x; a0f[5] = (bf16)f1.y; a0f[6] = (bf16)f1.z; a0f[7] = (bf16)f1.w;
  a1f[0] = (bf16)f2.x; a1f[1] = (bf16)f2.y; a1f[2] = (bf16)f2.z; a1f[3] = (bf16)f2.w;
  a1f[4] = (bf16)f3.x; a1f[5] = (bf16)f3.y; a1f[6] = (bf16)f3.z; a1f[7] = (bf16)f3.w;

  // K-proj MFMA + folded scores (C-layout: row=m*16+g*4+e, col=nt*16+c15)
  float s[4] = {0.f, 0.f, 0.f, 0.f};
#pragma unroll
  for (int nt = 0; nt < 4; ++nt) {
    bf16x8 bk0 = *reinterpret_cast<const bf16x8*>(fr + ((0 * 4 + nt) * 64 + lane) * 8);
    bf16x8 bk1 = *reinterpret_cast<const bf16x8*>(fr + ((1 * 4 + nt) * 64 + lane) * 8);
    f32x4 acc = {0.f, 0.f, 0.f, 0.f};
    acc = __builtin_amdgcn_mfma_f32_16x16x32_bf16(a0f, bk0, acc, 0, 0, 0);
    acc = __builtin_amdgcn_mfma_f32_16x16x32_bf16(a1f, bk1, acc, 0, 0, 0);
    float kb = bt[64 + nt * 16 + c15];
    float qpv = __shfl(qv_own, nt * 16 + c15, 64);
#pragma unroll
    for (int e = 0; e < 4; ++e) s[e] += fmaxf(acc[e] + kb, 0.f) * qpv;
  }
#pragma unroll
  for (int msk = 1; msk < 16; msk <<= 1)
#pragma unroll
    for (int e = 0; e < 4; ++e) s[e] += __shfl_xor(s[e], msk, 64);
  if (c15 == 0) {
#pragma unroll
    for (int e = 0; e < 4; ++e) scores[(size_t)ib * 64 + m * 16 + g * 4 + e] = s[e];
  }
}

// ---- K3: softmax over 50, in place (scores -> normalized probs) ------------
__global__ __launch_bounds__(256) void k_soft(float* __restrict__ scores) {
  int w = (blockIdx.x * 256 + threadIdx.x) >> 6;
  int lane = threadIdx.x & 63;
  float sv = (lane < S_NB) ? scores[(size_t)w * 64 + lane] : -1e30f;
  float mx = sv;
#pragma unroll
  for (int msk = 1; msk < 64; msk <<= 1) mx = fmaxf(mx, __shfl_xor(mx, msk, 64));
  float ev = (lane < S_NB) ? __expf((sv - mx) * 0.125f) : 0.f;
  float den = ev;
#pragma unroll
  for (int msk = 1; msk < 64; msk <<= 1) den += __shfl_xor(den, msk, 64);
  scores[(size_t)w * 64 + lane] = ev / den;
}

// ---- K4: V-proj MFMA + PV. one wave per (inst, b); loops m; reg accum. -----
__global__ __launch_bounds__(256) void k_pv(
    const int* __restrict__ uids, const int* __restrict__ qids,
    const int* __restrict__ mids, const int* __restrict__ u_movies,
    const int* __restrict__ m_querys, const int* __restrict__ m_users,
    const int* __restrict__ q_movies, const float* __restrict__ user_t,
    const float* __restrict__ item_t, const float* __restrict__ query_t,
    const float* __restrict__ gatB, const bf16* __restrict__ wfrag,
    const float* __restrict__ probs, float* __restrict__ y, int B) {
  int ib = (blockIdx.x * 256 + threadIdx.x) >> 6;
  int lane = threadIdx.x & 63;
  int inst = ib / B;
  int b = ib - inst * B;
  int c15 = lane & 15, g = lane >> 4;

  const int* idx; const float* nbt; int woff;
  if (inst == 0) { idx = u_movies; nbt = item_t; woff = 0; }
  else if (inst == 1) { idx = m_querys; nbt = query_t; woff = 1; }
  else if (inst == 2) { idx = m_users; nbt = user_t; woff = 1; }
  else { idx = q_movies; nbt = item_t; woff = 2; }
  const float* bt = gatB + woff * 256;
  const bf16* fr = wfrag + woff * 8192 + 4096;  // V frags

  float pv = probs[(size_t)ib * 64 + lane];  // normalized, 0 for rows >= 50
  float vb[4];
#pragma unroll
  for (int nt = 0; nt < 4; ++nt) vb[nt] = bt[128 + nt * 16 + c15];

  float yacc[4] = {0.f, 0.f, 0.f, 0.f};
#pragma unroll
  for (int m = 0; m < 4; ++m) {
    int arow = m * 16 + c15;
    int id = (arow < S_NB) ? idx[b * S_NB + arow] : 0;
    const float* rowp = nbt + (size_t)id * 64;
    float4 f0 = *reinterpret_cast<const float4*>(rowp + g * 8);
    float4 f1 = *reinterpret_cast<const float4*>(rowp + g * 8 + 4);
    float4 f2 = *reinterpret_cast<const float4*>(rowp + 32 + g * 8);
    float4 f3 = *reinterpret_cast<const float4*>(rowp + 32 + g * 8 + 4);
    bf16x8 a0f, a1f;
    a0f[0] = (bf16)f0.x; a0f[1] = (bf16)f0.y; a0f[2] = (bf16)f0.z; a0f[3] = (bf16)f0.w;
    a0f[4] = (bf16)f1.x; a0f[5] = (bf16)f1.y; a0f[6] = (bf16)f1.z; a0f[7] = (bf16)f1.w;
    a1f[0] = (bf16)f2.x; a1f[1] = (bf16)f2.y; a1f[2] = (bf16)f2.z; a1f[3] = (bf16)f2.w;
    a1f[4] = (bf16)f3.x; a1f[5] = (bf16)f3.y; a1f[6] = (bf16)f3.z; a1f[7] = (bf16)f3.w;
    float pw0 = __shfl(pv, m * 16 + g * 4 + 0, 64);
    float pw1 = __shfl(pv, m * 16 + g * 4 + 1, 64);
    float pw2 = __shfl(pv, m * 16 + g * 4 + 2, 64);
    float pw3 = __shfl(pv, m * 16 + g * 4 + 3, 64);
#pragma unroll
    for (int nt = 0; nt < 4; ++nt) {
      bf16x8 bv0 = *reinterpret_cast<const bf16x8*>(fr + ((0 * 4 + nt) * 64 + lane) * 8);
      bf16x8 bv1 = *reinterpret_cast<const bf16x8*>(fr + ((1 * 4 + nt) * 64 + lane) * 8);
      f32x4 acc = {0.f, 0.f, 0.f, 0.f};
      acc = __builtin_amdgcn_mfma_f32_16x16x32_bf16(a0f, bv0, acc, 0, 0, 0);
      acc = __builtin_amdgcn_mfma_f32_16x16x32_bf16(a1f, bv1, acc, 0, 0, 0);
      yacc[nt] += pw0 * fmaxf(acc[0] + vb[nt], 0.f) +
                  pw1 * fmaxf(acc[1] + vb[nt], 0.f) +
                  pw2 * fmaxf(acc[2] + vb[nt], 0.f) +
                  pw3 * fmaxf(acc[3] + vb[nt], 0.f);
    }
  }
#pragma unroll
  for (int nt = 0; nt < 4; ++nt) {
    yacc[nt] += __shfl_xor(yacc[nt], 16, 64);
    yacc[nt] += __shfl_xor(yacc[nt], 32, 64);
  }
  if (lane < 16) {
#pragma unroll
    for (int nt = 0; nt < 4; ++nt) y[(size_t)ib * 64 + nt * 16 + lane] = yacc[nt];
  }
}

// ---- K5: agg = relu(y @ W3 + b3). one thread per (inst, b, col). -----------
__global__ __launch_bounds__(256) void k_agg(
    const float* __restrict__ gatW, const float* __restrict__ gatB,
    const float* __restrict__ y, float* __restrict__ agg, int B) {
  int gid = blockIdx.x * 256 + threadIdx.x;
  int col = gid & 63;
  int ib = gid >> 6;
  int inst = ib / B;
  int woff = (inst == 0) ? 0 : ((inst == 3) ? 2 : 1);
  const float* W3 = gatW + (size_t)woff * 4 * 4096 + 3 * 4096;
  const float* yr = y + (size_t)ib * 64;
  float a0 = 0.f, a1 = 0.f, a2 = 0.f, a3 = 0.f;
#pragma unroll 4
  for (int k = 0; k < 64; k += 4) {
    a0 += yr[k] * W3[k * 64 + col];
    a1 += yr[k + 1] * W3[(k + 1) * 64 + col];
    a2 += yr[k + 2] * W3[(k + 2) * 64 + col];
    a3 += yr[k + 3] * W3[(k + 3) * 64 + col];
  }
  agg[gid] = fmaxf((((a0 + a1) + a2) + a3) + gatB[woff * 256 + 192 + col], 0.f);
}

// ---- K6: semantic attention. one wave per (tower, b). ----------------------
__global__ __launch_bounds__(256) void k_sem(
    const int* __restrict__ uids, const int* __restrict__ qids,
    const int* __restrict__ mids, const float* __restrict__ user_t,
    const float* __restrict__ item_t, const float* __restrict__ query_t,
    const float* __restrict__ semW, const float* __restrict__ semB,
    const float* __restrict__ agg, float* __restrict__ out, int B) {
  int w = (blockIdx.x * 256 + threadIdx.x) >> 6;
  int lane = threadIdx.x & 63;
  int t = w / B;
  int b = w - t * B;

  float nd, k1v, k2v;
  int ns;
  if (t == 0) {
    nd = user_t[(size_t)uids[b] * 64 + lane];
    k1v = agg[(size_t)(0 * B + b) * 64 + lane];
    k2v = k1v; ns = 2;
  } else if (t == 1) {
    nd = item_t[(size_t)mids[b] * 64 + lane];
    k1v = agg[(size_t)(1 * B + b) * 64 + lane];
    k2v = agg[(size_t)(2 * B + b) * 64 + lane];
    ns = 3;
  } else {
    nd = query_t[(size_t)qids[b] * 64 + lane];
    k1v = agg[(size_t)(3 * B + b) * 64 + lane];
    k2v = k1v; ns = 2;
  }
  const float* Ws = semW + (size_t)t * 4 * 4096;
  const float* bs = semB + t * 256;

  // qs = relu(node @ W0 + b0), col = lane
  float q0 = 0.f, q1 = 0.f;
#pragma unroll 4
  for (int k = 0; k < 64; k += 2) {
    q0 += __shfl(nd, k, 64) * Ws[k * 64 + lane];
    q1 += __shfl(nd, k + 1, 64) * Ws[(k + 1) * 64 + lane];
  }
  float qs = fmaxf(q0 + q1 + bs[lane], 0.f);

  // kp/vp rows for keys {node, k1, k2}
  const float* W1 = Ws + 4096;
  const float* W2 = Ws + 2 * 4096;
  float kp0 = 0.f, kp1 = 0.f, kp2 = 0.f, vp0 = 0.f, vp1 = 0.f, vp2 = 0.f;
#pragma unroll 2
  for (int k = 0; k < 64; ++k) {
    float w1 = W1[k * 64 + lane];
    float w2 = W2[k * 64 + lane];
    float nk = __shfl(nd, k, 64);
    float a1k = __shfl(k1v, k, 64);
    float a2k = __shfl(k2v, k, 64);
    kp0 += nk * w1; kp1 += a1k * w1; kp2 += a2k * w1;
    vp0 += nk * w2; vp1 += a1k * w2; vp2 += a2k * w2;
  }
  float bk = bs[64 + lane], bv = bs[128 + lane];
  kp0 = fmaxf(kp0 + bk, 0.f); kp1 = fmaxf(kp1 + bk, 0.f); kp2 = fmaxf(kp2 + bk, 0.f);
  vp0 = fmaxf(vp0 + bv, 0.f); vp1 = fmaxf(vp1 + bv, 0.f); vp2 = fmaxf(vp2 + bv, 0.f);

  // scores = dot(qs, kp_r)/8 via xor-tree
  float s0 = qs * kp0, s1 = qs * kp1, s2 = qs * kp2;
#pragma unroll
  for (int msk = 1; msk < 64; msk <<= 1) {
    s0 += __shfl_xor(s0, msk, 64);
    s1 += __shfl_xor(s1, msk, 64);
    s2 += __shfl_xor(s2, msk, 64);
  }
  s0 *= 0.125f; s1 *= 0.125f; s2 *= 0.125f;
  float mx = fmaxf(s0, s1);
  if (ns > 2) mx = fmaxf(mx, s2);
  float e0 = __expf(s0 - mx);
  float e1 = __expf(s1 - mx);
  float e2 = (ns > 2) ? __expf(s2 - mx) : 0.f;
  float rd = 1.f / (e0 + e1 + e2);
  float yv = (e0 * vp0 + e1 * vp1 + e2 * vp2) * rd;

  // out = relu(y @ W3 + b3)
  const float* W3 = Ws + 3 * 4096;
  float o0 = 0.f, o1 = 0.f;
#pragma unroll 4
  for (int k = 0; k < 64; k += 2) {
    o0 += __shfl(yv, k, 64) * W3[k * 64 + lane];
    o1 += __shfl(yv, k + 1, 64) * W3[(k + 1) * 64 + lane];
  }
  out[(size_t)b * 192 + t * 64 + lane] = fmaxf(o0 + o1 + bs[192 + lane], 0.f);
}

extern "C" void kernel_launch(void* const* d_in, const int* in_sizes, int n_in,
                              void* d_out, int out_size, void* d_ws, size_t ws_size,
                              hipStream_t stream) {
  const int* uids = (const int*)d_in[0];
  const int* qids = (const int*)d_in[1];
  const int* mids = (const int*)d_in[2];
  const int* u_movies = (const int*)d_in[3];
  const int* m_querys = (const int*)d_in[4];
  const int* m_users = (const int*)d_in[5];
  const int* q_movies = (const int*)d_in[6];
  const float* user_t = (const float*)d_in[7];
  const float* item_t = (const float*)d_in[8];
  const float* query_t = (const float*)d_in[9];
  const float* gatW = (const float*)d_in[10];
  const float* gatB = (const float*)d_in[11];
  const float* semW = (const float*)d_in[12];
  const float* semB = (const float*)d_in[13];
  float* out = (float*)d_out;

  int B = in_sizes[0];
  // ws layout (floats): [0,16384) wfrag bf16 (48KB); then scores, y, agg
  // each 4*B*64 floats. Total = 64KB + 3*16.78MB ≈ 50.4 MB.
  bf16* wfrag = (bf16*)d_ws;
  float* wsf = (float*)d_ws;
  size_t seg = (size_t)4 * B * 64;
  float* scores = wsf + 16384;
  float* y = scores + seg;
  float* agg = y + seg;

  shuffle_w<<<12, 256, 0, stream>>>(gatW, wfrag);
  k_scores<<<4 * B, 256, 0, stream>>>(uids, qids, mids, u_movies, m_querys,
                                      m_users, q_movies, user_t, item_t,
                                      query_t, gatW, gatB, wfrag, scores, B);
  k_soft<<<B, 256, 0, stream>>>(scores);
  k_pv<<<B, 256, 0, stream>>>(uids, qids, mids, u_movies, m_querys, m_users,
                              q_movies, user_t, item_t, query_t, gatB, wfrag,
                              scores, y, B);
  k_agg<<<B, 256, 0, stream>>>(gatW, gatB, y, agg, B);
  k_sem<<<3 * B / 4, 256, 0, stream>>>(uids, qids, mids, user_t, item_t,
                                       query_t, semW, semB, agg, out, B);
}

// Round 16
// 547.704 us; speedup vs baseline: 1.4259x; 1.4259x over previous
//
#include <hip/hip_runtime.h>

typedef __bf16 bf16;
typedef __bf16 bf16x8 __attribute__((ext_vector_type(8)));
typedef float f32x4 __attribute__((ext_vector_type(4)));

#define S_NB 50

// ---------------- weight pre-shuffle: f32 -> bf16 MFMA B-fragment layout ----
__global__ __launch_bounds__(256) void shuffle_w(const float* __restrict__ gatW,
                                                 bf16* __restrict__ ws) {
  int tid = blockIdx.x * 256 + threadIdx.x;
  if (tid >= 6 * 512) return;
  int mat = tid >> 9;
  int rem = tid & 511;
  int ks = rem >> 8;
  int nt = (rem >> 6) & 3;
  int lane = rem & 63;
  int t = mat >> 1, p = (mat & 1) + 1;
  const float* src = gatW + (size_t)(t * 4 + p) * 4096;
  int n = nt * 16 + (lane & 15);
  int kb = ks * 32 + (lane >> 4) * 8;
  bf16x8 v;
#pragma unroll
  for (int e = 0; e < 8; ++e) v[e] = (bf16)src[(kb + e) * 64 + n];
  *reinterpret_cast<bf16x8*>(ws + mat * 4096 + ((ks * 4 + nt) * 64 + lane) * 8) = v;
}

// inst mapping: 0:U(u_movies,item | node user[uids])  1:M(m_querys,query | item[mids])
//               2:M(m_users,user | item[mids])        3:Q(q_movies,item | query[qids])

// ---- K1: qp = relu(node @ W0 + b0), one thread per (inst, b, col). f32. ----
__global__ __launch_bounds__(256) void k_qp(
    const int* __restrict__ uids, const int* __restrict__ qids,
    const int* __restrict__ mids, const float* __restrict__ user_t,
    const float* __restrict__ item_t, const float* __restrict__ query_t,
    const float* __restrict__ gatW, const float* __restrict__ gatB,
    float* __restrict__ qp, int B) {
  int gid = blockIdx.x * 256 + threadIdx.x;
  int col = gid & 63;
  int ib = gid >> 6;
  int inst = ib / B;
  int b = ib - inst * B;

  const float* ndt; int ndid; int woff;
  if (inst == 0) { ndt = user_t; ndid = uids[b]; woff = 0; }
  else if (inst == 1) { ndt = item_t; ndid = mids[b]; woff = 1; }
  else if (inst == 2) { ndt = item_t; ndid = mids[b]; woff = 1; }
  else { ndt = query_t; ndid = qids[b]; woff = 2; }
  const float* Wt = gatW + (size_t)woff * 4 * 4096;
  const float* nd = ndt + (size_t)ndid * 64;

  float q0 = 0.f, q1 = 0.f, q2 = 0.f, q3 = 0.f;
#pragma unroll 4
  for (int k = 0; k < 64; k += 4) {
    q0 += nd[k] * Wt[k * 64 + col];
    q1 += nd[k + 1] * Wt[(k + 1) * 64 + col];
    q2 += nd[k + 2] * Wt[(k + 2) * 64 + col];
    q3 += nd[k + 3] * Wt[(k + 3) * 64 + col];
  }
  qp[gid] = fmaxf((((q0 + q1) + q2) + q3) + gatB[woff * 256 + col], 0.f);
}

// ---- K2: fused scores + softmax + PV. one wave per (inst, b). --------------
// A-fragments gathered ONCE, held in regs for both K-MFMA and V-MFMA passes.
__global__ __launch_bounds__(256) void k_gat(
    const int* __restrict__ uids, const int* __restrict__ qids,
    const int* __restrict__ mids, const int* __restrict__ u_movies,
    const int* __restrict__ m_querys, const int* __restrict__ m_users,
    const int* __restrict__ q_movies, const float* __restrict__ user_t,
    const float* __restrict__ item_t, const float* __restrict__ query_t,
    const float* __restrict__ gatB, const bf16* __restrict__ wfrag,
    const float* __restrict__ qp, float* __restrict__ y, int B) {
  int ib = (blockIdx.x * 256 + threadIdx.x) >> 6;
  int lane = threadIdx.x & 63;
  int inst = ib / B;
  int b = ib - inst * B;
  int c15 = lane & 15, g = lane >> 4;

  const int* idx; const float* nbt; int woff;
  if (inst == 0) { idx = u_movies; nbt = item_t; woff = 0; }
  else if (inst == 1) { idx = m_querys; nbt = query_t; woff = 1; }
  else if (inst == 2) { idx = m_users; nbt = user_t; woff = 1; }
  else { idx = q_movies; nbt = item_t; woff = 2; }
  const float* bt = gatB + woff * 256;
  const bf16* frk = wfrag + woff * 8192;        // K frags
  const bf16* frv = wfrag + woff * 8192 + 4096; // V frags

  // A fragments for all 4 m-tiles (rows 50..63 -> id 0 = zero row)
  bf16x8 af0[4], af1[4];
#pragma unroll
  for (int m = 0; m < 4; ++m) {
    int arow = m * 16 + c15;
    int id = (arow < S_NB) ? idx[b * S_NB + arow] : 0;
    const float* rowp = nbt + (size_t)id * 64;
    float4 f0 = *reinterpret_cast<const float4*>(rowp + g * 8);
    float4 f1 = *reinterpret_cast<const float4*>(rowp + g * 8 + 4);
    float4 f2 = *reinterpret_cast<const float4*>(rowp + 32 + g * 8);
    float4 f3 = *reinterpret_cast<const float4*>(rowp + 32 + g * 8 + 4);
    af0[m][0] = (bf16)f0.x; af0[m][1] = (bf16)f0.y; af0[m][2] = (bf16)f0.z; af0[m][3] = (bf16)f0.w;
    af0[m][4] = (bf16)f1.x; af0[m][5] = (bf16)f1.y; af0[m][6] = (bf16)f1.z; af0[m][7] = (bf16)f1.w;
    af1[m][0] = (bf16)f2.x; af1[m][1] = (bf16)f2.y; af1[m][2] = (bf16)f2.z; af1[m][3] = (bf16)f2.w;
    af1[m][4] = (bf16)f3.x; af1[m][5] = (bf16)f3.y; af1[m][6] = (bf16)f3.z; af1[m][7] = (bf16)f3.w;
  }

  float qv_own = qp[(size_t)ib * 64 + lane];

  // K phase: scores s[m][e] (row = m*16 + g*4 + e, summed over nt cols)
  float s[4][4];
#pragma unroll
  for (int m = 0; m < 4; ++m)
#pragma unroll
    for (int e = 0; e < 4; ++e) s[m][e] = 0.f;
#pragma unroll
  for (int nt = 0; nt < 4; ++nt) {
    bf16x8 bk0 = *reinterpret_cast<const bf16x8*>(frk + ((0 * 4 + nt) * 64 + lane) * 8);
    bf16x8 bk1 = *reinterpret_cast<const bf16x8*>(frk + ((1 * 4 + nt) * 64 + lane) * 8);
    float kb = bt[64 + nt * 16 + c15];
    float qpv = __shfl(qv_own, nt * 16 + c15, 64);
#pragma unroll
    for (int m = 0; m < 4; ++m) {
      f32x4 acc = {0.f, 0.f, 0.f, 0.f};
      acc = __builtin_amdgcn_mfma_f32_16x16x32_bf16(af0[m], bk0, acc, 0, 0, 0);
      acc = __builtin_amdgcn_mfma_f32_16x16x32_bf16(af1[m], bk1, acc, 0, 0, 0);
#pragma unroll
      for (int e = 0; e < 4; ++e) s[m][e] += fmaxf(acc[e] + kb, 0.f) * qpv;
    }
  }
#pragma unroll
  for (int msk = 1; msk < 16; msk <<= 1)
#pragma unroll
    for (int m = 0; m < 4; ++m)
#pragma unroll
      for (int e = 0; e < 4; ++e) s[m][e] += __shfl_xor(s[m][e], msk, 64);

  // transpose to per-lane score: lane wants row == lane
  int m_l = lane >> 4, e_l = lane & 3, gg = (lane & 15) >> 2;
  float sv = -1e30f;
#pragma unroll
  for (int m = 0; m < 4; ++m)
#pragma unroll
    for (int e = 0; e < 4; ++e) {
      float v = __shfl(s[m][e], gg * 16, 64);
      sv = (m_l == m && e_l == e) ? v : sv;
    }

  // softmax over 50 (scale 1/8 folded into exp), in-wave
  float svm = (lane < S_NB) ? sv : -1e30f;
  float mx = svm;
#pragma unroll
  for (int msk = 1; msk < 64; msk <<= 1) mx = fmaxf(mx, __shfl_xor(mx, msk, 64));
  float ev = (lane < S_NB) ? __expf((svm - mx) * 0.125f) : 0.f;
  float den = ev;
#pragma unroll
  for (int msk = 1; msk < 64; msk <<= 1) den += __shfl_xor(den, msk, 64);
  float pv = ev / den;

  // prob weights for PV: pw[m][e] = prob of row m*16 + g*4 + e
  float pwv[4][4];
#pragma unroll
  for (int m = 0; m < 4; ++m)
#pragma unroll
    for (int e = 0; e < 4; ++e) pwv[m][e] = __shfl(pv, m * 16 + g * 4 + e, 64);

  // V phase: PV accumulate (A-frags reused from registers)
  float yacc[4] = {0.f, 0.f, 0.f, 0.f};
#pragma unroll
  for (int nt = 0; nt < 4; ++nt) {
    bf16x8 bv0 = *reinterpret_cast<const bf16x8*>(frv + ((0 * 4 + nt) * 64 + lane) * 8);
    bf16x8 bv1 = *reinterpret_cast<const bf16x8*>(frv + ((1 * 4 + nt) * 64 + lane) * 8);
    float vb = bt[128 + nt * 16 + c15];
#pragma unroll
    for (int m = 0; m < 4; ++m) {
      f32x4 acc = {0.f, 0.f, 0.f, 0.f};
      acc = __builtin_amdgcn_mfma_f32_16x16x32_bf16(af0[m], bv0, acc, 0, 0, 0);
      acc = __builtin_amdgcn_mfma_f32_16x16x32_bf16(af1[m], bv1, acc, 0, 0, 0);
      yacc[nt] += pwv[m][0] * fmaxf(acc[0] + vb, 0.f) +
                  pwv[m][1] * fmaxf(acc[1] + vb, 0.f) +
                  pwv[m][2] * fmaxf(acc[2] + vb, 0.f) +
                  pwv[m][3] * fmaxf(acc[3] + vb, 0.f);
    }
  }
#pragma unroll
  for (int nt = 0; nt < 4; ++nt) {
    yacc[nt] += __shfl_xor(yacc[nt], 16, 64);
    yacc[nt] += __shfl_xor(yacc[nt], 32, 64);
  }
  if (lane < 16) {
#pragma unroll
    for (int nt = 0; nt < 4; ++nt) y[(size_t)ib * 64 + nt * 16 + lane] = yacc[nt];
  }
}

// ---- K3: agg = relu(y @ W3 + b3). one thread per (inst, b, col). -----------
__global__ __launch_bounds__(256) void k_agg(
    const float* __restrict__ gatW, const float* __restrict__ gatB,
    const float* __restrict__ y, float* __restrict__ agg, int B) {
  int gid = blockIdx.x * 256 + threadIdx.x;
  int col = gid & 63;
  int ib = gid >> 6;
  int inst = ib / B;
  int woff = (inst == 0) ? 0 : ((inst == 3) ? 2 : 1);
  const float* W3 = gatW + (size_t)woff * 4 * 4096 + 3 * 4096;
  const float* yr = y + (size_t)ib * 64;
  float a0 = 0.f, a1 = 0.f, a2 = 0.f, a3 = 0.f;
#pragma unroll 4
  for (int k = 0; k < 64; k += 4) {
    a0 += yr[k] * W3[k * 64 + col];
    a1 += yr[k + 1] * W3[(k + 1) * 64 + col];
    a2 += yr[k + 2] * W3[(k + 2) * 64 + col];
    a3 += yr[k + 3] * W3[(k + 3) * 64 + col];
  }
  agg[gid] = fmaxf((((a0 + a1) + a2) + a3) + gatB[woff * 256 + 192 + col], 0.f);
}

// ---- K4: semantic attention. one wave per (tower, b). ----------------------
__global__ __launch_bounds__(256) void k_sem(
    const int* __restrict__ uids, const int* __restrict__ qids,
    const int* __restrict__ mids, const float* __restrict__ user_t,
    const float* __restrict__ item_t, const float* __restrict__ query_t,
    const float* __restrict__ semW, const float* __restrict__ semB,
    const float* __restrict__ agg, float* __restrict__ out, int B) {
  int w = (blockIdx.x * 256 + threadIdx.x) >> 6;
  int lane = threadIdx.x & 63;
  int t = w / B;
  int b = w - t * B;

  float nd, k1v, k2v;
  int ns;
  if (t == 0) {
    nd = user_t[(size_t)uids[b] * 64 + lane];
    k1v = agg[(size_t)(0 * B + b) * 64 + lane];
    k2v = k1v; ns = 2;
  } else if (t == 1) {
    nd = item_t[(size_t)mids[b] * 64 + lane];
    k1v = agg[(size_t)(1 * B + b) * 64 + lane];
    k2v = agg[(size_t)(2 * B + b) * 64 + lane];
    ns = 3;
  } else {
    nd = query_t[(size_t)qids[b] * 64 + lane];
    k1v = agg[(size_t)(3 * B + b) * 64 + lane];
    k2v = k1v; ns = 2;
  }
  const float* Ws = semW + (size_t)t * 4 * 4096;
  const float* bs = semB + t * 256;

  // qs = relu(node @ W0 + b0), col = lane
  float q0 = 0.f, q1 = 0.f;
#pragma unroll 4
  for (int k = 0; k < 64; k += 2) {
    q0 += __shfl(nd, k, 64) * Ws[k * 64 + lane];
    q1 += __shfl(nd, k + 1, 64) * Ws[(k + 1) * 64 + lane];
  }
  float qs = fmaxf(q0 + q1 + bs[lane], 0.f);

  // kp/vp rows for keys {node, k1, k2}
  const float* W1 = Ws + 4096;
  const float* W2 = Ws + 2 * 4096;
  float kp0 = 0.f, kp1 = 0.f, kp2 = 0.f, vp0 = 0.f, vp1 = 0.f, vp2 = 0.f;
#pragma unroll 2
  for (int k = 0; k < 64; ++k) {
    float w1 = W1[k * 64 + lane];
    float w2 = W2[k * 64 + lane];
    float nk = __shfl(nd, k, 64);
    float a1k = __shfl(k1v, k, 64);
    float a2k = __shfl(k2v, k, 64);
    kp0 += nk * w1; kp1 += a1k * w1; kp2 += a2k * w1;
    vp0 += nk * w2; vp1 += a1k * w2; vp2 += a2k * w2;
  }
  float bk = bs[64 + lane], bv = bs[128 + lane];
  kp0 = fmaxf(kp0 + bk, 0.f); kp1 = fmaxf(kp1 + bk, 0.f); kp2 = fmaxf(kp2 + bk, 0.f);
  vp0 = fmaxf(vp0 + bv, 0.f); vp1 = fmaxf(vp1 + bv, 0.f); vp2 = fmaxf(vp2 + bv, 0.f);

  // scores = dot(qs, kp_r)/8 via xor-tree
  float s0 = qs * kp0, s1 = qs * kp1, s2 = qs * kp2;
#pragma unroll
  for (int msk = 1; msk < 64; msk <<= 1) {
    s0 += __shfl_xor(s0, msk, 64);
    s1 += __shfl_xor(s1, msk, 64);
    s2 += __shfl_xor(s2, msk, 64);
  }
  s0 *= 0.125f; s1 *= 0.125f; s2 *= 0.125f;
  float mx = fmaxf(s0, s1);
  if (ns > 2) mx = fmaxf(mx, s2);
  float e0 = __expf(s0 - mx);
  float e1 = __expf(s1 - mx);
  float e2 = (ns > 2) ? __expf(s2 - mx) : 0.f;
  float rd = 1.f / (e0 + e1 + e2);
  float yv = (e0 * vp0 + e1 * vp1 + e2 * vp2) * rd;

  // out = relu(y @ W3 + b3)
  const float* W3 = Ws + 3 * 4096;
  float o0 = 0.f, o1 = 0.f;
#pragma unroll 4
  for (int k = 0; k < 64; k += 2) {
    o0 += __shfl(yv, k, 64) * W3[k * 64 + lane];
    o1 += __shfl(yv, k + 1, 64) * W3[(k + 1) * 64 + lane];
  }
  out[(size_t)b * 192 + t * 64 + lane] = fmaxf(o0 + o1 + bs[192 + lane], 0.f);
}

extern "C" void kernel_launch(void* const* d_in, const int* in_sizes, int n_in,
                              void* d_out, int out_size, void* d_ws, size_t ws_size,
                              hipStream_t stream) {
  const int* uids = (const int*)d_in[0];
  const int* qids = (const int*)d_in[1];
  const int* mids = (const int*)d_in[2];
  const int* u_movies = (const int*)d_in[3];
  const int* m_querys = (const int*)d_in[4];
  const int* m_users = (const int*)d_in[5];
  const int* q_movies = (const int*)d_in[6];
  const float* user_t = (const float*)d_in[7];
  const float* item_t = (const float*)d_in[8];
  const float* query_t = (const float*)d_in[9];
  const float* gatW = (const float*)d_in[10];
  const float* gatB = (const float*)d_in[11];
  const float* semW = (const float*)d_in[12];
  const float* semB = (const float*)d_in[13];
  float* out = (float*)d_out;

  int B = in_sizes[0];
  // ws layout (floats): [0,16384) wfrag bf16 (48KB); then qp, y, agg
  // each 4*B*64 floats. Total ≈ 50.4 MB.
  bf16* wfrag = (bf16*)d_ws;
  float* wsf = (float*)d_ws;
  size_t seg = (size_t)4 * B * 64;
  float* qp = wsf + 16384;
  float* y = qp + seg;
  float* agg = y + seg;

  shuffle_w<<<12, 256, 0, stream>>>(gatW, wfrag);
  k_qp<<<B, 256, 0, stream>>>(uids, qids, mids, user_t, item_t, query_t,
                              gatW, gatB, qp, B);
  k_gat<<<B, 256, 0, stream>>>(uids, qids, mids, u_movies, m_querys, m_users,
                               q_movies, user_t, item_t, query_t, gatB, wfrag,
                               qp, y, B);
  k_agg<<<B, 256, 0, stream>>>(gatW, gatB, y, agg, B);
  k_sem<<<3 * B / 4, 256, 0, stream>>>(uids, qids, mids, user_t, item_t,
                                       query_t, semW, semB, agg, out, B);
}

// Round 17
// 470.440 us; speedup vs baseline: 1.6601x; 1.1642x over previous
//
#include <hip/hip_runtime.h>

typedef __bf16 bf16;
typedef __bf16 bf16x8 __attribute__((ext_vector_type(8)));
typedef float f32x4 __attribute__((ext_vector_type(4)));

#define S_NB 50

// ---------------- weight pre-shuffle: f32 -> bf16 MFMA B-fragment layout ----
__global__ __launch_bounds__(256) void shuffle_w(const float* __restrict__ gatW,
                                                 bf16* __restrict__ ws) {
  int tid = blockIdx.x * 256 + threadIdx.x;
  if (tid >= 6 * 512) return;
  int mat = tid >> 9;
  int rem = tid & 511;
  int ks = rem >> 8;
  int nt = (rem >> 6) & 3;
  int lane = rem & 63;
  int t = mat >> 1, p = (mat & 1) + 1;
  const float* src = gatW + (size_t)(t * 4 + p) * 4096;
  int n = nt * 16 + (lane & 15);
  int kb = ks * 32 + (lane >> 4) * 8;
  bf16x8 v;
#pragma unroll
  for (int e = 0; e < 8; ++e) v[e] = (bf16)src[(kb + e) * 64 + n];
  *reinterpret_cast<bf16x8*>(ws + mat * 4096 + ((ks * 4 + nt) * 64 + lane) * 8) = v;
}

// inst mapping: 0:U(u_movies,item | node user[uids])  1:M(m_querys,query | item[mids])
//               2:M(m_users,user | item[mids])        3:Q(q_movies,item | query[qids])

// ---- gat_all: qp + scores + softmax + PV + agg, one wave per (inst, b). ----
__global__ __launch_bounds__(256) void gat_all(
    const int* __restrict__ uids, const int* __restrict__ qids,
    const int* __restrict__ mids, const int* __restrict__ u_movies,
    const int* __restrict__ m_querys, const int* __restrict__ m_users,
    const int* __restrict__ q_movies, const float* __restrict__ user_t,
    const float* __restrict__ item_t, const float* __restrict__ query_t,
    const float* __restrict__ gatW, const float* __restrict__ gatB,
    const bf16* __restrict__ wfrag, float* __restrict__ agg, int B) {
  int ib = (blockIdx.x * 256 + threadIdx.x) >> 6;
  int lane = threadIdx.x & 63;
  int inst = ib / B;
  int b = ib - inst * B;
  int c15 = lane & 15, g = lane >> 4;

  const int* idx; const float* nbt; const float* ndt; int ndid; int woff;
  if (inst == 0) { idx = u_movies; nbt = item_t; ndt = user_t; ndid = uids[b]; woff = 0; }
  else if (inst == 1) { idx = m_querys; nbt = query_t; ndt = item_t; ndid = mids[b]; woff = 1; }
  else if (inst == 2) { idx = m_users; nbt = user_t; ndt = item_t; ndid = mids[b]; woff = 1; }
  else { idx = q_movies; nbt = item_t; ndt = query_t; ndid = qids[b]; woff = 2; }
  const float* Wt = gatW + (size_t)woff * 4 * 4096;
  const float* bt = gatB + woff * 256;
  const bf16* frk = wfrag + woff * 8192;        // K frags
  const bf16* frv = wfrag + woff * 8192 + 4096; // V frags

  // node row (one 256B gather per wave)
  float nd = ndt[(size_t)ndid * 64 + lane];

  // A fragments for all 4 m-tiles (rows 50..63 -> id 0 = zero row)
  bf16x8 af0[4], af1[4];
#pragma unroll
  for (int m = 0; m < 4; ++m) {
    int arow = m * 16 + c15;
    int id = (arow < S_NB) ? idx[b * S_NB + arow] : 0;
    const float* rowp = nbt + (size_t)id * 64;
    float4 f0 = *reinterpret_cast<const float4*>(rowp + g * 8);
    float4 f1 = *reinterpret_cast<const float4*>(rowp + g * 8 + 4);
    float4 f2 = *reinterpret_cast<const float4*>(rowp + 32 + g * 8);
    float4 f3 = *reinterpret_cast<const float4*>(rowp + 32 + g * 8 + 4);
    af0[m][0] = (bf16)f0.x; af0[m][1] = (bf16)f0.y; af0[m][2] = (bf16)f0.z; af0[m][3] = (bf16)f0.w;
    af0[m][4] = (bf16)f1.x; af0[m][5] = (bf16)f1.y; af0[m][6] = (bf16)f1.z; af0[m][7] = (bf16)f1.w;
    af1[m][0] = (bf16)f2.x; af1[m][1] = (bf16)f2.y; af1[m][2] = (bf16)f2.z; af1[m][3] = (bf16)f2.w;
    af1[m][4] = (bf16)f3.x; af1[m][5] = (bf16)f3.y; af1[m][6] = (bf16)f3.z; af1[m][7] = (bf16)f3.w;
  }

  // qp[col=lane] = relu(node @ W0 + b0), node broadcast via shuffle
  // (same 4-accumulator order as r16's k_qp -> identical numerics)
  float qv_own;
  {
    float q0 = 0.f, q1 = 0.f, q2 = 0.f, q3 = 0.f;
#pragma unroll 4
    for (int k = 0; k < 64; k += 4) {
      q0 += __shfl(nd, k, 64) * Wt[k * 64 + lane];
      q1 += __shfl(nd, k + 1, 64) * Wt[(k + 1) * 64 + lane];
      q2 += __shfl(nd, k + 2, 64) * Wt[(k + 2) * 64 + lane];
      q3 += __shfl(nd, k + 3, 64) * Wt[(k + 3) * 64 + lane];
    }
    qv_own = fmaxf((((q0 + q1) + q2) + q3) + bt[lane], 0.f);
  }

  // K phase: scores s[m][e] (row = m*16 + g*4 + e, summed over nt cols)
  float s[4][4];
#pragma unroll
  for (int m = 0; m < 4; ++m)
#pragma unroll
    for (int e = 0; e < 4; ++e) s[m][e] = 0.f;
#pragma unroll
  for (int nt = 0; nt < 4; ++nt) {
    bf16x8 bk0 = *reinterpret_cast<const bf16x8*>(frk + ((0 * 4 + nt) * 64 + lane) * 8);
    bf16x8 bk1 = *reinterpret_cast<const bf16x8*>(frk + ((1 * 4 + nt) * 64 + lane) * 8);
    float kb = bt[64 + nt * 16 + c15];
    float qpv = __shfl(qv_own, nt * 16 + c15, 64);
#pragma unroll
    for (int m = 0; m < 4; ++m) {
      f32x4 acc = {0.f, 0.f, 0.f, 0.f};
      acc = __builtin_amdgcn_mfma_f32_16x16x32_bf16(af0[m], bk0, acc, 0, 0, 0);
      acc = __builtin_amdgcn_mfma_f32_16x16x32_bf16(af1[m], bk1, acc, 0, 0, 0);
#pragma unroll
      for (int e = 0; e < 4; ++e) s[m][e] += fmaxf(acc[e] + kb, 0.f) * qpv;
    }
  }
#pragma unroll
  for (int msk = 1; msk < 16; msk <<= 1)
#pragma unroll
    for (int m = 0; m < 4; ++m)
#pragma unroll
      for (int e = 0; e < 4; ++e) s[m][e] += __shfl_xor(s[m][e], msk, 64);

  // transpose to per-lane score: lane wants row == lane
  int m_l = lane >> 4, e_l = lane & 3, gg = (lane & 15) >> 2;
  float sv = -1e30f;
#pragma unroll
  for (int m = 0; m < 4; ++m)
#pragma unroll
    for (int e = 0; e < 4; ++e) {
      float v = __shfl(s[m][e], gg * 16, 64);
      sv = (m_l == m && e_l == e) ? v : sv;
    }

  // softmax over 50 (scale 1/8 folded into exp), in-wave
  float svm = (lane < S_NB) ? sv : -1e30f;
  float mx = svm;
#pragma unroll
  for (int msk = 1; msk < 64; msk <<= 1) mx = fmaxf(mx, __shfl_xor(mx, msk, 64));
  float ev = (lane < S_NB) ? __expf((svm - mx) * 0.125f) : 0.f;
  float den = ev;
#pragma unroll
  for (int msk = 1; msk < 64; msk <<= 1) den += __shfl_xor(den, msk, 64);
  float pv = ev / den;

  // prob weights for PV: pw[m][e] = prob of row m*16 + g*4 + e
  float pwv[4][4];
#pragma unroll
  for (int m = 0; m < 4; ++m)
#pragma unroll
    for (int e = 0; e < 4; ++e) pwv[m][e] = __shfl(pv, m * 16 + g * 4 + e, 64);

  // V phase: PV accumulate (A-frags reused from registers)
  float yacc[4] = {0.f, 0.f, 0.f, 0.f};
#pragma unroll
  for (int nt = 0; nt < 4; ++nt) {
    bf16x8 bv0 = *reinterpret_cast<const bf16x8*>(frv + ((0 * 4 + nt) * 64 + lane) * 8);
    bf16x8 bv1 = *reinterpret_cast<const bf16x8*>(frv + ((1 * 4 + nt) * 64 + lane) * 8);
    float vb = bt[128 + nt * 16 + c15];
#pragma unroll
    for (int m = 0; m < 4; ++m) {
      f32x4 acc = {0.f, 0.f, 0.f, 0.f};
      acc = __builtin_amdgcn_mfma_f32_16x16x32_bf16(af0[m], bv0, acc, 0, 0, 0);
      acc = __builtin_amdgcn_mfma_f32_16x16x32_bf16(af1[m], bv1, acc, 0, 0, 0);
      yacc[nt] += pwv[m][0] * fmaxf(acc[0] + vb, 0.f) +
                  pwv[m][1] * fmaxf(acc[1] + vb, 0.f) +
                  pwv[m][2] * fmaxf(acc[2] + vb, 0.f) +
                  pwv[m][3] * fmaxf(acc[3] + vb, 0.f);
    }
  }
#pragma unroll
  for (int nt = 0; nt < 4; ++nt) {
    yacc[nt] += __shfl_xor(yacc[nt], 16, 64);
    yacc[nt] += __shfl_xor(yacc[nt], 32, 64);
  }
  // after xor 16/32, lane l holds yacc[nt] = y[nt*16 + (l&15)] for every l.

  // agg = relu(y @ W3 + b3), col = lane (same 4-acc order as r16's k_agg)
  {
    const float* W3 = Wt + 3 * 4096;
    float a0 = 0.f, a1 = 0.f, a2 = 0.f, a3 = 0.f;
#pragma unroll
    for (int k = 0; k < 64; k += 4) {
      a0 += __shfl(yacc[(k + 0) >> 4], (k + 0) & 15, 64) * W3[(k + 0) * 64 + lane];
      a1 += __shfl(yacc[(k + 1) >> 4], (k + 1) & 15, 64) * W3[(k + 1) * 64 + lane];
      a2 += __shfl(yacc[(k + 2) >> 4], (k + 2) & 15, 64) * W3[(k + 2) * 64 + lane];
      a3 += __shfl(yacc[(k + 3) >> 4], (k + 3) & 15, 64) * W3[(k + 3) * 64 + lane];
    }
    agg[(size_t)ib * 64 + lane] =
        fmaxf((((a0 + a1) + a2) + a3) + gatB[woff * 256 + 192 + lane], 0.f);
  }
}

// ---- k_sem: semantic attention. one wave per (tower, b). -------------------
__global__ __launch_bounds__(256) void k_sem(
    const int* __restrict__ uids, const int* __restrict__ qids,
    const int* __restrict__ mids, const float* __restrict__ user_t,
    const float* __restrict__ item_t, const float* __restrict__ query_t,
    const float* __restrict__ semW, const float* __restrict__ semB,
    const float* __restrict__ agg, float* __restrict__ out, int B) {
  int w = (blockIdx.x * 256 + threadIdx.x) >> 6;
  int lane = threadIdx.x & 63;
  int t = w / B;
  int b = w - t * B;

  float nd, k1v, k2v;
  int ns;
  if (t == 0) {
    nd = user_t[(size_t)uids[b] * 64 + lane];
    k1v = agg[(size_t)(0 * B + b) * 64 + lane];
    k2v = k1v; ns = 2;
  } else if (t == 1) {
    nd = item_t[(size_t)mids[b] * 64 + lane];
    k1v = agg[(size_t)(1 * B + b) * 64 + lane];
    k2v = agg[(size_t)(2 * B + b) * 64 + lane];
    ns = 3;
  } else {
    nd = query_t[(size_t)qids[b] * 64 + lane];
    k1v = agg[(size_t)(3 * B + b) * 64 + lane];
    k2v = k1v; ns = 2;
  }
  const float* Ws = semW + (size_t)t * 4 * 4096;
  const float* bs = semB + t * 256;

  // qs = relu(node @ W0 + b0), col = lane
  float q0 = 0.f, q1 = 0.f;
#pragma unroll 4
  for (int k = 0; k < 64; k += 2) {
    q0 += __shfl(nd, k, 64) * Ws[k * 64 + lane];
    q1 += __shfl(nd, k + 1, 64) * Ws[(k + 1) * 64 + lane];
  }
  float qs = fmaxf(q0 + q1 + bs[lane], 0.f);

  // kp/vp rows for keys {node, k1, k2}
  const float* W1 = Ws + 4096;
  const float* W2 = Ws + 2 * 4096;
  float kp0 = 0.f, kp1 = 0.f, kp2 = 0.f, vp0 = 0.f, vp1 = 0.f, vp2 = 0.f;
#pragma unroll 2
  for (int k = 0; k < 64; ++k) {
    float w1 = W1[k * 64 + lane];
    float w2 = W2[k * 64 + lane];
    float nk = __shfl(nd, k, 64);
    float a1k = __shfl(k1v, k, 64);
    float a2k = __shfl(k2v, k, 64);
    kp0 += nk * w1; kp1 += a1k * w1; kp2 += a2k * w1;
    vp0 += nk * w2; vp1 += a1k * w2; vp2 += a2k * w2;
  }
  float bk = bs[64 + lane], bv = bs[128 + lane];
  kp0 = fmaxf(kp0 + bk, 0.f); kp1 = fmaxf(kp1 + bk, 0.f); kp2 = fmaxf(kp2 + bk, 0.f);
  vp0 = fmaxf(vp0 + bv, 0.f); vp1 = fmaxf(vp1 + bv, 0.f); vp2 = fmaxf(vp2 + bv, 0.f);

  // scores = dot(qs, kp_r)/8 via xor-tree
  float s0 = qs * kp0, s1 = qs * kp1, s2 = qs * kp2;
#pragma unroll
  for (int msk = 1; msk < 64; msk <<= 1) {
    s0 += __shfl_xor(s0, msk, 64);
    s1 += __shfl_xor(s1, msk, 64);
    s2 += __shfl_xor(s2, msk, 64);
  }
  s0 *= 0.125f; s1 *= 0.125f; s2 *= 0.125f;
  float mx = fmaxf(s0, s1);
  if (ns > 2) mx = fmaxf(mx, s2);
  float e0 = __expf(s0 - mx);
  float e1 = __expf(s1 - mx);
  float e2 = (ns > 2) ? __expf(s2 - mx) : 0.f;
  float rd = 1.f / (e0 + e1 + e2);
  float yv = (e0 * vp0 + e1 * vp1 + e2 * vp2) * rd;

  // out = relu(y @ W3 + b3)
  const float* W3 = Ws + 3 * 4096;
  float o0 = 0.f, o1 = 0.f;
#pragma unroll 4
  for (int k = 0; k < 64; k += 2) {
    o0 += __shfl(yv, k, 64) * W3[k * 64 + lane];
    o1 += __shfl(yv, k + 1, 64) * W3[(k + 1) * 64 + lane];
  }
  out[(size_t)b * 192 + t * 64 + lane] = fmaxf(o0 + o1 + bs[192 + lane], 0.f);
}

extern "C" void kernel_launch(void* const* d_in, const int* in_sizes, int n_in,
                              void* d_out, int out_size, void* d_ws, size_t ws_size,
                              hipStream_t stream) {
  const int* uids = (const int*)d_in[0];
  const int* qids = (const int*)d_in[1];
  const int* mids = (const int*)d_in[2];
  const int* u_movies = (const int*)d_in[3];
  const int* m_querys = (const int*)d_in[4];
  const int* m_users = (const int*)d_in[5];
  const int* q_movies = (const int*)d_in[6];
  const float* user_t = (const float*)d_in[7];
  const float* item_t = (const float*)d_in[8];
  const float* query_t = (const float*)d_in[9];
  const float* gatW = (const float*)d_in[10];
  const float* gatB = (const float*)d_in[11];
  const float* semW = (const float*)d_in[12];
  const float* semB = (const float*)d_in[13];
  float* out = (float*)d_out;

  int B = in_sizes[0];
  // ws layout (floats): [0,16384) wfrag bf16 (48KB); then agg (4*B*64 f32).
  bf16* wfrag = (bf16*)d_ws;
  float* wsf = (float*)d_ws;
  float* agg = wsf + 16384;

  shuffle_w<<<12, 256, 0, stream>>>(gatW, wfrag);
  gat_all<<<B, 256, 0, stream>>>(uids, qids, mids, u_movies, m_querys,
                                 m_users, q_movies, user_t, item_t, query_t,
                                 gatW, gatB, wfrag, agg, B);
  k_sem<<<3 * B / 4, 256, 0, stream>>>(uids, qids, mids, user_t, item_t,
                                       query_t, semW, semB, agg, out, B);
}